// Round 1
// baseline (4081.754 us; speedup 1.0000x reference)
//
#include <hip/hip_runtime.h>
#include <stdint.h>

#define N_POINTS 400000
#define WIDTH    64
#define M_SAMPLES 1000          // N_POINTS / 400
#define NBLK 64
#define NTHR 1024
#define NTOT (NBLK * NTHR)      // 65536 threads
#define PPT  7                  // ceil(400000 / 65536)

// 64-bit shuffle via two 32-bit shuffles (avoids relying on u64 overload)
__device__ inline unsigned long long shfl_down_u64(unsigned long long x, int off) {
    unsigned int lo = (unsigned int)x;
    unsigned int hi = (unsigned int)(x >> 32);
    lo = __shfl_down(lo, off, 64);
    hi = __shfl_down(hi, off, 64);
    return ((unsigned long long)hi << 32) | lo;
}

__global__ void fps_init(unsigned long long* slot, int* out) {
    int t = blockIdx.x * blockDim.x + threadIdx.x;
    if (t < M_SAMPLES * NBLK) slot[t] = 0ull;
    if (t == 0) out[0] = 0;     // seed index
}

__global__ __launch_bounds__(NTHR)
void fps_main(const float* __restrict__ feats, int* __restrict__ out,
              unsigned long long* __restrict__ slot)
{
    const int tid = threadIdx.x;
    const int bid = blockIdx.x;
    const int gid = bid * NTHR + tid;

    // Register-resident points + running min-squared-distance
    float px[PPT], py[PPT], pz[PPT], dd[PPT];
#pragma unroll
    for (int k = 0; k < PPT; k++) {
        int j = gid + k * NTOT;
        if (j < N_POINTS) {
            px[k] = feats[(size_t)j * WIDTH + 0];
            py[k] = feats[(size_t)j * WIDTH + 1];
            pz[k] = feats[(size_t)j * WIDTH + 2];
        } else {
            px[k] = 0.f; py[k] = 0.f; pz[k] = 0.f;
        }
        dd[k] = 1e10f;          // matches jnp.full(..., 1e10, f32)
    }

    __shared__ unsigned long long s_red[NTHR / 64];
    __shared__ unsigned long long s_key;

    int last = 0;
    for (int i = 1; i < M_SAMPLES; i++) {
        // Broadcast load of the pivot point (uniform address -> L1 broadcast)
        float qx = feats[(size_t)last * WIDTH + 0];
        float qy = feats[(size_t)last * WIDTH + 1];
        float qz = feats[(size_t)last * WIDTH + 2];

        unsigned long long best = 0ull;
#pragma unroll
        for (int k = 0; k < PPT; k++) {
            int j = gid + k * NTOT;
            // IEEE ops in reference order; _rn intrinsics block fp-contract
            float dx = __fsub_rn(px[k], qx);
            float dy = __fsub_rn(py[k], qy);
            float dz = __fsub_rn(pz[k], qz);
            float d  = __fadd_rn(__fadd_rn(__fmul_rn(dx, dx), __fmul_rn(dy, dy)),
                                 __fmul_rn(dz, dz));
            float nd = fminf(dd[k], d);
            dd[k] = nd;
            if (j < N_POINTS) {
                // key: dist bits (non-negative -> monotone) high, (N - idx) low
                // => max key = max dist, ties broken toward LOWER index (argmax semantics)
                unsigned long long key =
                    ((unsigned long long)__float_as_uint(nd) << 32) |
                    (unsigned int)(N_POINTS - j);
                if (key > best) best = key;
            }
        }

        // Wave-level reduction (64 lanes)
#pragma unroll
        for (int off = 32; off > 0; off >>= 1) {
            unsigned long long o = shfl_down_u64(best, off);
            if (o > best) best = o;
        }
        if ((tid & 63) == 0) s_red[tid >> 6] = best;
        __syncthreads();

        if (tid < 64) {
            // Block-level reduction in wave 0
            unsigned long long b2 = (tid < (NTHR / 64)) ? s_red[tid] : 0ull;
#pragma unroll
            for (int off = 32; off > 0; off >>= 1) {
                unsigned long long o = shfl_down_u64(b2, off);
                if (o > b2) b2 = o;
            }
            if (tid == 0) {
                __hip_atomic_store(&slot[(size_t)i * NBLK + bid], b2,
                                   __ATOMIC_RELEASE, __HIP_MEMORY_SCOPE_AGENT);
            }
            // Lane b polls block b's slot for this iteration; all-to-all winner compute
            const unsigned long long* sl = &slot[(size_t)i * NBLK];
            unsigned long long v = 0ull;
            while (true) {
                if (v == 0ull)
                    v = __hip_atomic_load(&sl[tid], __ATOMIC_ACQUIRE,
                                          __HIP_MEMORY_SCOPE_AGENT);
                if (__ballot(v != 0ull) == ~0ull) break;
                __builtin_amdgcn_s_sleep(1);
            }
#pragma unroll
            for (int off = 32; off > 0; off >>= 1) {
                unsigned long long o = shfl_down_u64(v, off);
                if (o > v) v = o;
            }
            if (tid == 0) {
                s_key = v;
                if (bid == 0)
                    out[i] = (int)(N_POINTS - (unsigned int)(v & 0xffffffffull));
            }
        }
        __syncthreads();
        last = (int)(N_POINTS - (unsigned int)(s_key & 0xffffffffull));
    }
}

extern "C" void kernel_launch(void* const* d_in, const int* in_sizes, int n_in,
                              void* d_out, int out_size, void* d_ws, size_t ws_size,
                              hipStream_t stream) {
    const float* feats = (const float*)d_in[0];
    int* out = (int*)d_out;
    unsigned long long* slot = (unsigned long long*)d_ws;  // M_SAMPLES*NBLK u64 = 512 KB

    fps_init<<<(M_SAMPLES * NBLK + 255) / 256, 256, 0, stream>>>(slot, out);
    // 64 blocks x 1024 thr: <= 1 block/CU on 256 CUs -> co-residency guaranteed
    fps_main<<<NBLK, NTHR, 0, stream>>>(feats, out, slot);
}

// Round 2
// 3810.503 us; speedup vs baseline: 1.0712x; 1.0712x over previous
//
#include <hip/hip_runtime.h>
#include <stdint.h>

#define N_POINTS 400000
#define WIDTH    64
#define M_SAMPLES 1000          // N_POINTS / 400
#define NBLK 64
#define NTHR 256
#define NTOT (NBLK * NTHR)      // 16384 threads
#define PPT  25                 // ceil(400000 / 16384)

// 64-bit shuffle via two 32-bit shuffles
__device__ inline unsigned long long shfl_down_u64(unsigned long long x, int off) {
    unsigned int lo = (unsigned int)x;
    unsigned int hi = (unsigned int)(x >> 32);
    lo = __shfl_down(lo, off, 64);
    hi = __shfl_down(hi, off, 64);
    return ((unsigned long long)hi << 32) | lo;
}

__global__ void fps_init(unsigned long long* slot, int* out) {
    int t = blockIdx.x * blockDim.x + threadIdx.x;
    if (t < M_SAMPLES * NBLK) slot[t] = 0ull;
    if (t == 0) out[0] = 0;     // seed index
}

__global__ __launch_bounds__(NTHR)
void fps_main(const float* __restrict__ feats, int* __restrict__ out,
              unsigned long long* __restrict__ slot)
{
    const int tid = threadIdx.x;
    const int bid = blockIdx.x;
    const int gid = bid * NTHR + tid;

    // Register-resident points + running min-squared-distance
    float px[PPT], py[PPT], pz[PPT], dd[PPT];
#pragma unroll
    for (int k = 0; k < PPT; k++) {
        int j = gid + k * NTOT;
        if (j < N_POINTS) {
            px[k] = feats[(size_t)j * WIDTH + 0];
            py[k] = feats[(size_t)j * WIDTH + 1];
            pz[k] = feats[(size_t)j * WIDTH + 2];
        } else {
            px[k] = 0.f; py[k] = 0.f; pz[k] = 0.f;
        }
        dd[k] = 1e10f;          // matches jnp.full(..., 1e10, f32)
    }

    __shared__ unsigned long long s_red[NTHR / 64];
    __shared__ unsigned long long s_key;

    int last = 0;
    for (int i = 1; i < M_SAMPLES; i++) {
        // Pivot coords (wave-uniform address; L1/L2-hit thanks to spin prefetch)
        float qx = feats[(size_t)last * WIDTH + 0];
        float qy = feats[(size_t)last * WIDTH + 1];
        float qz = feats[(size_t)last * WIDTH + 2];

        unsigned long long best = 0ull;
#pragma unroll
        for (int k = 0; k < PPT; k++) {
            int j = gid + k * NTOT;
            // IEEE ops in reference order; _rn intrinsics block fp-contract
            float dx = __fsub_rn(px[k], qx);
            float dy = __fsub_rn(py[k], qy);
            float dz = __fsub_rn(pz[k], qz);
            float d  = __fadd_rn(__fadd_rn(__fmul_rn(dx, dx), __fmul_rn(dy, dy)),
                                 __fmul_rn(dz, dz));
            float nd = fminf(dd[k], d);
            dd[k] = nd;
            if (j < N_POINTS) {
                // key: dist bits high (non-negative float -> monotone u32),
                // (N - idx) low => max key = max dist, ties -> lowest index
                unsigned long long key =
                    ((unsigned long long)__float_as_uint(nd) << 32) |
                    (unsigned int)(N_POINTS - j);
                if (key > best) best = key;
            }
        }

        // Wave-level reduction (64 lanes)
#pragma unroll
        for (int off = 32; off > 0; off >>= 1) {
            unsigned long long o = shfl_down_u64(best, off);
            if (o > best) best = o;
        }
        if ((tid & 63) == 0) s_red[tid >> 6] = best;
        __syncthreads();

        if (tid < 64) {
            // Block-level reduction in wave 0
            unsigned long long b2 = (tid < (NTHR / 64)) ? s_red[tid] : 0ull;
#pragma unroll
            for (int off = 32; off > 0; off >>= 1) {
                unsigned long long o = shfl_down_u64(b2, off);
                if (o > b2) b2 = o;
            }
            // RELAXED store: payload is entirely inside the 64-bit value,
            // no ordering needed -> no buffer_wbl2 on the critical path.
            if (tid == 0) {
                __hip_atomic_store(&slot[(size_t)i * NBLK + bid], b2,
                                   __ATOMIC_RELAXED, __HIP_MEMORY_SCOPE_AGENT);
            }
            // Lane b polls block b's slot (RELAXED: no buffer_inv per poll).
            // While waiting, prefetch the candidate pivot's cache line so the
            // post-consensus feats load is a cache hit.
            const unsigned long long* sl = &slot[(size_t)i * NBLK];
            unsigned long long v = 0ull;
            bool prefetched = false;
            while (true) {
                if (v == 0ull)
                    v = __hip_atomic_load(&sl[tid], __ATOMIC_RELAXED,
                                          __HIP_MEMORY_SCOPE_AGENT);
                if (v != 0ull && !prefetched) {
                    int cand = (int)(N_POINTS - (unsigned int)(v & 0xffffffffull));
                    float t = feats[(size_t)cand * WIDTH];
                    asm volatile("" :: "v"(t));   // keep the load; warms L1/L2
                    prefetched = true;
                }
                if (__ballot(v != 0ull) == ~0ull) break;
                __builtin_amdgcn_s_sleep(2);
            }
#pragma unroll
            for (int off = 32; off > 0; off >>= 1) {
                unsigned long long o = shfl_down_u64(v, off);
                if (o > v) v = o;
            }
            if (tid == 0) {
                s_key = v;
                if (bid == 0)
                    out[i] = (int)(N_POINTS - (unsigned int)(v & 0xffffffffull));
            }
        }
        __syncthreads();
        last = (int)(N_POINTS - (unsigned int)(s_key & 0xffffffffull));
    }
}

extern "C" void kernel_launch(void* const* d_in, const int* in_sizes, int n_in,
                              void* d_out, int out_size, void* d_ws, size_t ws_size,
                              hipStream_t stream) {
    const float* feats = (const float*)d_in[0];
    int* out = (int*)d_out;
    unsigned long long* slot = (unsigned long long*)d_ws;  // M_SAMPLES*NBLK u64 = 512 KB

    fps_init<<<(M_SAMPLES * NBLK + 255) / 256, 256, 0, stream>>>(slot, out);
    // 64 blocks x 256 thr: 1 block/CU max -> co-residency guaranteed
    fps_main<<<NBLK, NTHR, 0, stream>>>(feats, out, slot);
}

// Round 3
// 3049.546 us; speedup vs baseline: 1.3385x; 1.2495x over previous
//
#include <hip/hip_runtime.h>
#include <stdint.h>

#define N_POINTS  400000
#define WIDTH     64
#define M_SAMPLES 1000          // N_POINTS / 400
#define NBLK      64
#define NTHR      256
#define NW        (NTHR / 64)   // 4 waves per block
#define NSLOT     (NBLK * NW)   // 256 candidate slots per iteration
#define NTOT      (NBLK * NTHR) // 16384 threads
#define PPT       25            // ceil(400000 / 16384)

// 64-bit xor-shuffle via two 32-bit shuffles (butterfly -> all lanes get max)
__device__ inline unsigned long long shfl_xor_u64(unsigned long long x, int m) {
    unsigned int lo = (unsigned int)x;
    unsigned int hi = (unsigned int)(x >> 32);
    lo = __shfl_xor(lo, m, 64);
    hi = __shfl_xor(hi, m, 64);
    return ((unsigned long long)hi << 32) | lo;
}

__global__ void fps_init(unsigned long long* slot, int* out) {
    int t = blockIdx.x * blockDim.x + threadIdx.x;
    if (t < M_SAMPLES * NSLOT) slot[t] = 0ull;
    if (t == 0) out[0] = 0;     // seed index
}

// Workspace requirement: M_SAMPLES * NSLOT * 8 B = 2,048,000 B (~2 MB) in d_ws.
__global__ __launch_bounds__(NTHR)
void fps_main(const float* __restrict__ feats, int* __restrict__ out,
              unsigned long long* __restrict__ slot)
{
    const int tid  = threadIdx.x;
    const int bid  = blockIdx.x;
    const int lane = tid & 63;
    const int wid  = tid >> 6;
    const int gid  = bid * NTHR + tid;

    // Register-resident points + running min squared distance
    float px[PPT], py[PPT], pz[PPT], dd[PPT];
#pragma unroll
    for (int k = 0; k < PPT; k++) {
        int j = gid + k * NTOT;
        if (j < N_POINTS) {
            px[k] = feats[(size_t)j * WIDTH + 0];
            py[k] = feats[(size_t)j * WIDTH + 1];
            pz[k] = feats[(size_t)j * WIDTH + 2];
        } else {
            px[k] = 0.f; py[k] = 0.f; pz[k] = 0.f;
        }
        dd[k] = 1e10f;          // matches jnp.full(..., 1e10, f32)
    }

    __shared__ unsigned long long s_key;

    int last = 0;
    for (int i = 1; i < M_SAMPLES; i++) {
        // Pivot coords (wave-uniform address)
        float qx = feats[(size_t)last * WIDTH + 0];
        float qy = feats[(size_t)last * WIDTH + 1];
        float qz = feats[(size_t)last * WIDTH + 2];

        unsigned long long best = 0ull;
#pragma unroll
        for (int k = 0; k < PPT; k++) {
            int j = gid + k * NTOT;
            // IEEE ops in reference order; _rn intrinsics block fp-contract
            float dx = __fsub_rn(px[k], qx);
            float dy = __fsub_rn(py[k], qy);
            float dz = __fsub_rn(pz[k], qz);
            float d  = __fadd_rn(__fadd_rn(__fmul_rn(dx, dx), __fmul_rn(dy, dy)),
                                 __fmul_rn(dz, dz));
            float nd = fminf(dd[k], d);
            dd[k] = nd;
            if (j < N_POINTS) {
                // key: dist bits high (non-negative float -> monotone u32),
                // (N - idx) low (nonzero!) => max key = max dist, ties -> lowest idx
                unsigned long long key =
                    ((unsigned long long)__float_as_uint(nd) << 32) |
                    (unsigned int)(N_POINTS - j);
                if (key > best) best = key;
            }
        }

        // In-register wave butterfly max (all lanes end with wave max)
#pragma unroll
        for (int m = 32; m > 0; m >>= 1) {
            unsigned long long o = shfl_xor_u64(best, m);
            if (o > best) best = o;
        }

        // Per-WAVE candidate store: straight from registers, no LDS/barrier hop.
        if (lane == 0) {
            __hip_atomic_store(&slot[(size_t)i * NSLOT + bid * NW + wid], best,
                               __ATOMIC_RELAXED, __HIP_MEMORY_SCOPE_AGENT);
        }

        if (wid == 0) {
            // Lane l polls the 4 slots of block l (contiguous 32 B).
            const unsigned long long* sl = slot + (size_t)i * NSLOT + lane * NW;
            unsigned long long k0 = 0, k1 = 0, k2 = 0, k3 = 0;
            do {
                if (!k0) k0 = __hip_atomic_load(sl + 0, __ATOMIC_RELAXED,
                                                __HIP_MEMORY_SCOPE_AGENT);
                if (!k1) k1 = __hip_atomic_load(sl + 1, __ATOMIC_RELAXED,
                                                __HIP_MEMORY_SCOPE_AGENT);
                if (!k2) k2 = __hip_atomic_load(sl + 2, __ATOMIC_RELAXED,
                                                __HIP_MEMORY_SCOPE_AGENT);
                if (!k3) k3 = __hip_atomic_load(sl + 3, __ATOMIC_RELAXED,
                                                __HIP_MEMORY_SCOPE_AGENT);
            } while (!(k0 && k1 && k2 && k3));

            unsigned long long v = k0;
            if (k1 > v) v = k1;
            if (k2 > v) v = k2;
            if (k3 > v) v = k3;
#pragma unroll
            for (int m = 32; m > 0; m >>= 1) {
                unsigned long long o = shfl_xor_u64(v, m);
                if (o > v) v = o;
            }
            if (lane == 0) {
                s_key = v;
                if (bid == 0)
                    out[i] = (int)(N_POINTS - (unsigned int)(v & 0xffffffffull));
            }
        }
        // Single barrier: waves 1-3 arrive early (right after their store);
        // wave 0 releases it as soon as s_key is written.
        __syncthreads();
        last = (int)(N_POINTS - (unsigned int)(s_key & 0xffffffffull));
    }
}

extern "C" void kernel_launch(void* const* d_in, const int* in_sizes, int n_in,
                              void* d_out, int out_size, void* d_ws, size_t ws_size,
                              hipStream_t stream) {
    const float* feats = (const float*)d_in[0];
    int* out = (int*)d_out;
    unsigned long long* slot = (unsigned long long*)d_ws;  // ~2 MB used

    fps_init<<<(M_SAMPLES * NSLOT + 255) / 256, 256, 0, stream>>>(slot, out);
    // 64 blocks x 256 thr: 1 block/CU -> co-residency guaranteed
    fps_main<<<NBLK, NTHR, 0, stream>>>(feats, out, slot);
}